// Round 9
// baseline (893.750 us; speedup 1.0000x reference)
//
#include <hip/hip_runtime.h>
#include <hip/hip_bf16.h>
#include <math.h>

// GCN link predictor: N=100000 nodes, d=128, E=1.6M edges, EL=200K label edges.
// Round 9: binning (R8) was LDS-atomic-serialization bound (348K bank-conflict
// cycles, 4.8% occupancy, 181us). Replace the whole CSR build with
// range-partitioned STREAMING (scatter->gather inversion):
//   deg3_kern: block b owns ~391 nodes; streams whole dst[] (int4, coalesced,
//              per-XCD L2-shared) and histograms its range in LDS.
//   fill3_kern: same, LDS holds absolute cursors (row_off-seeded); csr writes
//              land in the block's ~55KB window -> L2 accumulates full lines.
// Eliminates zero2/deg_count/fill scattered atomics entirely.
//
// Workspace layout (bytes):
//   0        dinv    float[N]      (400 KB)
//   512K     deg     int[N]        (400 KB)
//   1024K    row_off int[N+1]      (400 KB)
//   1536K    cursor  int[N]        (400 KB, fallback path only)
//   2048K    csr     int[E]        (6.4 MB)
//   8704K    bsum    int[128]
//   24M      hbuf    bf16[N*128]   (25.6 MB)
//   56M      zbuf    float[N*128]  (51.2 MB)

#define WAVE 64
#define SCAN_CHUNK 1024   // elements per block (256 threads x 4)
#define GK 32             // gemm k-chunk
#define FB 256            // fill/deg blocks (one per CU)
#define FT 512            // threads per fill/deg block (8 waves/CU)
#define MAXRANGE 1024     // max nodes per block range (N <= FB*MAXRANGE)

// ---- bf16 pack/unpack (RNE) ----
__device__ __forceinline__ unsigned bf16_rne(float f) {
    unsigned u = __float_as_uint(f);
    return (u + 0x7FFFu + ((u >> 16) & 1u)) >> 16;
}
__device__ __forceinline__ uint2 pack4_bf16(float4 v) {
    uint2 o;
    o.x = bf16_rne(v.x) | (bf16_rne(v.y) << 16);
    o.y = bf16_rne(v.z) | (bf16_rne(v.w) << 16);
    return o;
}
__device__ __forceinline__ float4 unpack4_bf16(uint2 p) {
    float4 o;
    o.x = __uint_as_float(p.x << 16);
    o.y = __uint_as_float(p.x & 0xFFFF0000u);
    o.z = __uint_as_float(p.y << 16);
    o.w = __uint_as_float(p.y & 0xFFFF0000u);
    return o;
}

// ---- range-partitioned degree histogram ----
__global__ __launch_bounds__(FT) void deg3_kern(const int* __restrict__ dst,
                                                int* __restrict__ deg, int N, int E) {
    __shared__ int cnt[MAXRANGE];
    int b = blockIdx.x;
    int lo = (int)(((long long)N * b) / FB);
    int hi = (int)(((long long)N * (b + 1)) / FB);
    int len = hi - lo;
    for (int i = threadIdx.x; i < len; i += FT) cnt[i] = 0;
    __syncthreads();
    int E4 = E >> 2;
    const int4* d4 = (const int4*)dst;
    for (int i = threadIdx.x; i < E4; i += FT) {
        int4 v = d4[i];
        if ((unsigned)(v.x - lo) < (unsigned)len) atomicAdd(&cnt[v.x - lo], 1);
        if ((unsigned)(v.y - lo) < (unsigned)len) atomicAdd(&cnt[v.y - lo], 1);
        if ((unsigned)(v.z - lo) < (unsigned)len) atomicAdd(&cnt[v.z - lo], 1);
        if ((unsigned)(v.w - lo) < (unsigned)len) atomicAdd(&cnt[v.w - lo], 1);
    }
    for (int i = (E4 << 2) + threadIdx.x; i < E; i += FT) {
        int d = dst[i];
        if ((unsigned)(d - lo) < (unsigned)len) atomicAdd(&cnt[d - lo], 1);
    }
    __syncthreads();
    for (int i = threadIdx.x; i < len; i += FT) deg[lo + i] = cnt[i];
}

// ---- range-partitioned CSR fill (LDS absolute cursors) ----
__global__ __launch_bounds__(FT) void fill3_kern(const int* __restrict__ src,
                                                 const int* __restrict__ dst,
                                                 const int* __restrict__ row_off,
                                                 int* __restrict__ csr, int N, int E) {
    __shared__ int cur[MAXRANGE];
    int b = blockIdx.x;
    int lo = (int)(((long long)N * b) / FB);
    int hi = (int)(((long long)N * (b + 1)) / FB);
    int len = hi - lo;
    for (int i = threadIdx.x; i < len; i += FT) cur[i] = row_off[lo + i];
    __syncthreads();
    int E4 = E >> 2;
    const int4* d4 = (const int4*)dst;
    const int4* s4 = (const int4*)src;
    for (int i = threadIdx.x; i < E4; i += FT) {
        int4 dv = d4[i];
        int4 sv = s4[i];
        if ((unsigned)(dv.x - lo) < (unsigned)len) { int p = atomicAdd(&cur[dv.x - lo], 1); csr[p] = sv.x; }
        if ((unsigned)(dv.y - lo) < (unsigned)len) { int p = atomicAdd(&cur[dv.y - lo], 1); csr[p] = sv.y; }
        if ((unsigned)(dv.z - lo) < (unsigned)len) { int p = atomicAdd(&cur[dv.z - lo], 1); csr[p] = sv.z; }
        if ((unsigned)(dv.w - lo) < (unsigned)len) { int p = atomicAdd(&cur[dv.w - lo], 1); csr[p] = sv.w; }
    }
    for (int i = (E4 << 2) + threadIdx.x; i < E; i += FT) {
        int d = dst[i];
        if ((unsigned)(d - lo) < (unsigned)len) { int p = atomicAdd(&cur[d - lo], 1); csr[p] = src[i]; }
    }
}

// ---- fallback path (N too large for range partitioning) ----
__global__ __launch_bounds__(256) void zero2_kern(int* __restrict__ a,
                                                  int* __restrict__ b, int N) {
    int i = blockIdx.x * blockDim.x + threadIdx.x;
    if (i < N) { a[i] = 0; b[i] = 0; }
}
__global__ __launch_bounds__(256) void deg_count_kern(const int* __restrict__ dst,
                                                      int* __restrict__ deg, int E) {
    int i = blockIdx.x * blockDim.x + threadIdx.x;
    if (i < E) atomicAdd(&deg[dst[i]], 1);
}
__global__ __launch_bounds__(256) void fill_kern(const int* __restrict__ src,
                                                 const int* __restrict__ dst,
                                                 const int* __restrict__ row_off,
                                                 int* __restrict__ cursor,
                                                 int* __restrict__ csr, int E) {
    int e = blockIdx.x * blockDim.x + threadIdx.x;
    if (e >= E) return;
    int d = dst[e];
    int p = atomicAdd(&cursor[d], 1);
    csr[row_off[d] + p] = src[e];
}

__device__ __forceinline__ int load4_sum(const int* __restrict__ deg, int base, int N,
                                         int4* out) {
    int4 v = make_int4(0, 0, 0, 0);
    if (base + 3 < N) {
        v = ((const int4*)deg)[base >> 2];
    } else {
        if (base + 0 < N) v.x = deg[base + 0];
        if (base + 1 < N) v.y = deg[base + 1];
        if (base + 2 < N) v.z = deg[base + 2];
        if (base + 3 < N) v.w = deg[base + 3];
    }
    *out = v;
    return v.x + v.y + v.z + v.w;
}

// Per-block partial sums of deg.
__global__ __launch_bounds__(256) void scan_part_kern(const int* __restrict__ deg,
                                                      int* __restrict__ bsum, int N) {
    __shared__ int sdata[256];
    int t = threadIdx.x;
    int base = blockIdx.x * SCAN_CHUNK + t * 4;
    int4 v;
    int sum = load4_sum(deg, base, N, &v);
    sdata[t] = sum;
    __syncthreads();
#pragma unroll
    for (int off = 128; off > 0; off >>= 1) {
        if (t < off) sdata[t] += sdata[t + off];
        __syncthreads();
    }
    if (t == 0) bsum[blockIdx.x] = sdata[0];
}

// Single small block: exclusive scan of nb (<=128) block sums; row_off[N]=total.
__global__ __launch_bounds__(128) void scan_top_kern(int* __restrict__ bsum,
                                                     int* __restrict__ row_off,
                                                     int nb, int N) {
    __shared__ int sdata[128];
    int t = threadIdx.x;
    int own = (t < nb) ? bsum[t] : 0;
    sdata[t] = own;
    __syncthreads();
#pragma unroll
    for (int off = 1; off < 128; off <<= 1) {
        int v = sdata[t];
        int add = (t >= off) ? sdata[t - off] : 0;
        __syncthreads();
        sdata[t] = v + add;
        __syncthreads();
    }
    if (t < nb) bsum[t] = sdata[t] - own;   // exclusive
    if (t == 127) row_off[N] = sdata[127];  // total == E
}

// Re-scan locally, add block offset, write row_off + dinv.
__global__ __launch_bounds__(256) void scan_apply_kern(const int* __restrict__ deg,
                                                       const int* __restrict__ bsum,
                                                       int* __restrict__ row_off,
                                                       float* __restrict__ dinv, int N) {
    __shared__ int sdata[256];
    int t = threadIdx.x;
    int base = blockIdx.x * SCAN_CHUNK + t * 4;
    int4 v;
    int sum = load4_sum(deg, base, N, &v);
    sdata[t] = sum;
    __syncthreads();
#pragma unroll
    for (int off = 1; off < 256; off <<= 1) {
        int x = sdata[t];
        int add = (t >= off) ? sdata[t - off] : 0;
        __syncthreads();
        sdata[t] = x + add;
        __syncthreads();
    }
    int run = bsum[blockIdx.x] + sdata[t] - sum;  // global exclusive prefix
    if (base + 0 < N) { row_off[base + 0] = run; dinv[base + 0] = rsqrtf((float)(v.x + 1)); run += v.x; }
    if (base + 1 < N) { row_off[base + 1] = run; dinv[base + 1] = rsqrtf((float)(v.y + 1)); run += v.y; }
    if (base + 2 < N) { row_off[base + 2] = run; dinv[base + 2] = rsqrtf((float)(v.z + 1)); run += v.z; }
    if (base + 3 < N) { row_off[base + 3] = run; dinv[base + 3] = rsqrtf((float)(v.w + 1)); }
}

// H[M,128](bf16) = X[M,128](fp32) @ W[128,128](fp32). 64 rows x 128 cols/block.
// K chunked by GK=32: LDS = 24 KB -> 6 blocks/CU.
__global__ __launch_bounds__(256) void gemm128_kern(const float* __restrict__ X,
                                                    const float* __restrict__ W,
                                                    uint2* __restrict__ H16, int M) {
    __shared__ float xs[64][GK];      // 8 KB
    __shared__ float wsm[GK][128];    // 16 KB
    int tid = threadIdx.x;
    int block_row = blockIdx.x * 64;
    int tx = tid & 31;
    int ty = tid >> 5;

    float4 acc[8];
#pragma unroll
    for (int i = 0; i < 8; ++i) acc[i] = make_float4(0.f, 0.f, 0.f, 0.f);

    for (int k0 = 0; k0 < 128; k0 += GK) {
        __syncthreads();  // protect previous chunk's LDS reads
        {
            const float4* W4 = (const float4*)(W + (size_t)k0 * 128);
            float4* w4 = (float4*)wsm;
#pragma unroll
            for (int i = 0; i < 4; ++i) w4[tid + 256 * i] = W4[tid + 256 * i];
        }
        {
#pragma unroll
            for (int i = 0; i < 2; ++i) {
                int idx = tid + 256 * i;   // 0..511
                int r = idx >> 3;          // 0..63
                int c = idx & 7;           // float4 within chunk
                int grow = block_row + r;
                float4 v = make_float4(0.f, 0.f, 0.f, 0.f);
                if (grow < M) v = ((const float4*)X)[(size_t)grow * 32 + (k0 >> 2) + c];
                ((float4*)xs)[idx] = v;
            }
        }
        __syncthreads();

#pragma unroll 4
        for (int kk = 0; kk < GK; ++kk) {
            float4 wv = ((float4*)&wsm[kk][0])[tx];
            float xr[8];
#pragma unroll
            for (int i = 0; i < 8; ++i) xr[i] = xs[ty * 8 + i][kk];
#pragma unroll
            for (int i = 0; i < 8; ++i) {
                acc[i].x = fmaf(xr[i], wv.x, acc[i].x);
                acc[i].y = fmaf(xr[i], wv.y, acc[i].y);
                acc[i].z = fmaf(xr[i], wv.z, acc[i].z);
                acc[i].w = fmaf(xr[i], wv.w, acc[i].w);
            }
        }
    }

#pragma unroll
    for (int i = 0; i < 8; ++i) {
        int grow = block_row + ty * 8 + i;
        if (grow < M) H16[(size_t)grow * 32 + tx] = pack4_bf16(acc[i]);
    }
}

// One wave per node, h in bf16 (256 B rows). 16-edge chunks: per-lane load
// src + dinv[src], shfl {src, norm}, 8 independent half-split uint2 gathers.
__global__ __launch_bounds__(256) void agg_kern(const int* __restrict__ row_off,
                                                const int* __restrict__ csr,
                                                const float* __restrict__ dinv,
                                                const uint2* __restrict__ h16,
                                                const float* __restrict__ bias,
                                                void* __restrict__ z,
                                                int N, int do_relu, int out_bf16) {
    int wave = (blockIdx.x * blockDim.x + threadIdx.x) >> 6;
    int lane = threadIdx.x & (WAVE - 1);
    if (wave >= N) return;
    int v = wave;
    int half = lane >> 5;    // lanes 0-31: even edge slots, 32-63: odd slots
    int l32 = lane & 31;
    int beg = row_off[v];
    int degv = row_off[v + 1] - beg;
    float dv = dinv[v];

    float4 acc = make_float4(0.f, 0.f, 0.f, 0.f);

    for (int base = 0; base < degv; base += WAVE) {
        int cnt = degv - base; if (cnt > WAVE) cnt = WAVE;
        int s_lane = 0;
        float n_lane = 0.f;
        if (lane < cnt) {
            s_lane = csr[beg + base + lane];       // coalesced
            n_lane = dinv[s_lane] * dv;            // dinv: 400 KB, L2-resident
        }
        for (int j = 0; j < cnt; j += 16) {
            int   sidx[8];
            float nn[8];
#pragma unroll
            for (int u = 0; u < 8; ++u) {
                int sl = j + 2 * u + half;          // slot in [j, j+16)
                sidx[u] = __shfl(s_lane, sl);
                nn[u]   = __shfl(n_lane, sl);
            }
            uint2 hv[8];
#pragma unroll
            for (int u = 0; u < 8; ++u)             // 8 independent 512 B gathers
                hv[u] = h16[(size_t)sidx[u] * 32 + l32];
#pragma unroll
            for (int u = 0; u < 8; ++u) {
                float4 f = unpack4_bf16(hv[u]);
                acc.x = fmaf(f.x, nn[u], acc.x);
                acc.y = fmaf(f.y, nn[u], acc.y);
                acc.z = fmaf(f.z, nn[u], acc.z);
                acc.w = fmaf(f.w, nn[u], acc.w);
            }
        }
    }

    // combine the two halves (lane^32)
    acc.x += __shfl_xor(acc.x, 32, 64);
    acc.y += __shfl_xor(acc.y, 32, 64);
    acc.z += __shfl_xor(acc.z, 32, 64);
    acc.w += __shfl_xor(acc.w, 32, 64);

    float ss = dv * dv;
    float4 hv = unpack4_bf16(h16[(size_t)v * 32 + l32]);
    float4 bv = ((const float4*)bias)[l32];
    acc.x = fmaf(hv.x, ss, acc.x) + bv.x;
    acc.y = fmaf(hv.y, ss, acc.y) + bv.y;
    acc.z = fmaf(hv.z, ss, acc.z) + bv.z;
    acc.w = fmaf(hv.w, ss, acc.w) + bv.w;
    if (do_relu) {
        acc.x = fmaxf(acc.x, 0.f); acc.y = fmaxf(acc.y, 0.f);
        acc.z = fmaxf(acc.z, 0.f); acc.w = fmaxf(acc.w, 0.f);
    }
    if (half == 0) {
        if (out_bf16) ((uint2*)z)[(size_t)v * 32 + l32] = pack4_bf16(acc);
        else          ((float4*)z)[(size_t)v * 32 + l32] = acc;
    }
}

// Four label edges per wave (2 per half-wave), z2 in bf16 (256 B rows).
__global__ __launch_bounds__(256) void decode_kern(const int* __restrict__ s_idx,
                                                   const int* __restrict__ d_idx,
                                                   const uint2* __restrict__ z16,
                                                   float* __restrict__ out, int EL) {
    int lane = threadIdx.x & (WAVE - 1);
    int wave = (blockIdx.x * blockDim.x + threadIdx.x) >> 6;
    int half = lane >> 5;
    int l32 = lane & 31;
    int e0 = wave * 4 + half;      // this half-wave handles e0 and e0+2
    int e1 = e0 + 2;

    int s0 = 0, d0 = 0, s1 = 0, d1 = 0;
    if (e0 < EL) { s0 = s_idx[e0]; d0 = d_idx[e0]; }
    if (e1 < EL) { s1 = s_idx[e1]; d1 = d_idx[e1]; }
    uint2 pa0 = z16[(size_t)s0 * 32 + l32];
    uint2 pb0 = z16[(size_t)d0 * 32 + l32];
    uint2 pa1 = z16[(size_t)s1 * 32 + l32];
    uint2 pb1 = z16[(size_t)d1 * 32 + l32];
    float4 a0 = unpack4_bf16(pa0), b0 = unpack4_bf16(pb0);
    float4 a1 = unpack4_bf16(pa1), b1 = unpack4_bf16(pb1);
    float p0 = a0.x * b0.x + a0.y * b0.y + a0.z * b0.z + a0.w * b0.w;
    float p1 = a1.x * b1.x + a1.y * b1.y + a1.z * b1.z + a1.w * b1.w;
#pragma unroll
    for (int off = 16; off > 0; off >>= 1) {
        p0 += __shfl_xor(p0, off, 64);   // stays within the 32-lane half
        p1 += __shfl_xor(p1, off, 64);
    }
    if (l32 == 0) {
        if (e0 < EL) out[e0] = p0;
        if (e1 < EL) out[e1] = p1;
    }
}

extern "C" void kernel_launch(void* const* d_in, const int* in_sizes, int n_in,
                              void* d_out, int out_size, void* d_ws, size_t ws_size,
                              hipStream_t stream) {
    const float* x   = (const float*)d_in[0];
    const int*   ei  = (const int*)d_in[1];
    const int*   eli = (const int*)d_in[2];
    const float* W1  = (const float*)d_in[3];
    const float* b1  = (const float*)d_in[4];
    const float* W2  = (const float*)d_in[5];
    const float* b2  = (const float*)d_in[6];
    float* out = (float*)d_out;

    int N  = in_sizes[0] / 128;
    int E  = in_sizes[1] / 2;
    int EL = in_sizes[2] / 2;
    const int* src = ei;
    const int* dst = ei + E;
    const int* ls  = eli;
    const int* ld  = eli + EL;

    char* ws = (char*)d_ws;
    float* dinv    = (float*)(ws);
    int*   deg     = (int*)(ws + (512 << 10));
    int*   row_off = (int*)(ws + (1024 << 10));
    int*   cursor  = (int*)(ws + (1536 << 10));   // fallback path only
    int*   csr     = (int*)(ws + (2048 << 10));   // ends ~8.5 MB
    int*   bsum    = (int*)(ws + (8704 << 10));
    uint2* hbuf    = (uint2*)(ws + (24u << 20));  // bf16 h (25.6 MB)
    char*  zraw    = ws + (56u << 20);            // z1 fp32 / z2 bf16 (51.2 MB)
    float* z1      = (float*)zraw;
    uint2* z2      = (uint2*)zraw;

    int nodeGrid = (N + 255) / 256;
    int edgeGrid = (E + 255) / 256;
    int gemmGrid = (N + 63) / 64;
    int aggGrid  = (N + 3) / 4;   // 4 waves/block, 1 wave/node
    int nbScan   = (N + SCAN_CHUNK - 1) / SCAN_CHUNK;  // 98 for N=100K (<=128)

    // CSR build (shared by both layers)
    bool rangeOK = (N <= FB * MAXRANGE);
    if (rangeOK) {
        deg3_kern<<<FB, FT, 0, stream>>>(dst, deg, N, E);
    } else {
        zero2_kern<<<nodeGrid, 256, 0, stream>>>(deg, cursor, N);
        deg_count_kern<<<edgeGrid, 256, 0, stream>>>(dst, deg, E);
    }
    scan_part_kern<<<nbScan, 256, 0, stream>>>(deg, bsum, N);
    scan_top_kern<<<1, 128, 0, stream>>>(bsum, row_off, nbScan, N);
    scan_apply_kern<<<nbScan, 256, 0, stream>>>(deg, bsum, row_off, dinv, N);
    if (rangeOK) {
        fill3_kern<<<FB, FT, 0, stream>>>(src, dst, row_off, csr, N, E);
    } else {
        fill_kern<<<edgeGrid, 256, 0, stream>>>(src, dst, row_off, cursor, csr, E);
    }

    // layer 1: h1(bf16) = x @ W1 ; z1(fp32) = relu(agg(h1) + b1)
    gemm128_kern<<<gemmGrid, 256, 0, stream>>>(x, W1, hbuf, N);
    agg_kern<<<aggGrid, 256, 0, stream>>>(row_off, csr, dinv, hbuf, b1, (void*)z1, N, 1, 0);

    // layer 2: h2(bf16) = z1 @ W2 ; z2(bf16) = agg(h2) + b2
    gemm128_kern<<<gemmGrid, 256, 0, stream>>>(z1, W2, hbuf, N);
    agg_kern<<<aggGrid, 256, 0, stream>>>(row_off, csr, dinv, hbuf, b2, (void*)z2, N, 0, 1);

    // decode: 4 edges per wave, bf16 gathers
    decode_kern<<<(EL + 15) / 16, 256, 0, stream>>>(ls, ld, z2, out, EL);
}

// Round 10
// 482.081 us; speedup vs baseline: 1.8539x; 1.8539x over previous
//
#include <hip/hip_runtime.h>
#include <hip/hip_bf16.h>
#include <math.h>

// GCN link predictor: N=100000 nodes, d=128, E=1.6M edges, EL=200K label edges.
// Round 10: revert to R6 pipeline (proven 508us); replace only fill_kern with
// fill4_kern: dst-range-filtered scatter. 8 dst-ranges x 32 edge-slices = 256
// blocks; block b -> range b%8 (matches XCD under round-robin dispatch) and
// slice b/8. Each XCD streams the 12.8MB edge list once (L3-shared, ~8x amp
// vs R9's fatal 256x) and scatters only into its own 800KB csr window + 50KB
// cursor slice -> L2-resident, full-line writebacks (~6.4MB vs 107MB).
// scan_apply now seeds cursor with ABSOLUTE csr offsets (row_off copy).
//
// Workspace layout (bytes):
//   0        dinv    float[N]      (400 KB)
//   512K     deg     int[N]        (400 KB)
//   1024K    row_off int[N+1]      (400 KB)
//   1536K    cursor  int[N]        (400 KB)
//   2048K    csr     int[E]        (6.4 MB)
//   8704K    bsum    int[128]
//   24M      hbuf    bf16[N*128]   (25.6 MB)
//   56M      zbuf    float[N*128]  (51.2 MB)

#define WAVE 64
#define SCAN_CHUNK 1024   // elements per block (256 threads x 4)
#define GK 32             // gemm k-chunk
#define NRANGE 8          // dst ranges (= XCD count heuristic)
#define NSLICE 32         // edge slices per range
#define FT4 512           // threads per fill4 block

// ---- bf16 pack/unpack (RNE) ----
__device__ __forceinline__ unsigned bf16_rne(float f) {
    unsigned u = __float_as_uint(f);
    return (u + 0x7FFFu + ((u >> 16) & 1u)) >> 16;
}
__device__ __forceinline__ uint2 pack4_bf16(float4 v) {
    uint2 o;
    o.x = bf16_rne(v.x) | (bf16_rne(v.y) << 16);
    o.y = bf16_rne(v.z) | (bf16_rne(v.w) << 16);
    return o;
}
__device__ __forceinline__ float4 unpack4_bf16(uint2 p) {
    float4 o;
    o.x = __uint_as_float(p.x << 16);
    o.y = __uint_as_float(p.x & 0xFFFF0000u);
    o.z = __uint_as_float(p.y << 16);
    o.w = __uint_as_float(p.y & 0xFFFF0000u);
    return o;
}

__global__ __launch_bounds__(256) void zero1_kern(int* __restrict__ a, int N) {
    int i = blockIdx.x * blockDim.x + threadIdx.x;
    if (i < N) a[i] = 0;
}

__global__ __launch_bounds__(256) void deg_count_kern(const int* __restrict__ dst,
                                                      int* __restrict__ deg, int E) {
    int i = blockIdx.x * blockDim.x + threadIdx.x;
    if (i < E) atomicAdd(&deg[dst[i]], 1);
}

__device__ __forceinline__ int load4_sum(const int* __restrict__ deg, int base, int N,
                                         int4* out) {
    int4 v = make_int4(0, 0, 0, 0);
    if (base + 3 < N) {
        v = ((const int4*)deg)[base >> 2];
    } else {
        if (base + 0 < N) v.x = deg[base + 0];
        if (base + 1 < N) v.y = deg[base + 1];
        if (base + 2 < N) v.z = deg[base + 2];
        if (base + 3 < N) v.w = deg[base + 3];
    }
    *out = v;
    return v.x + v.y + v.z + v.w;
}

// Per-block partial sums of deg.
__global__ __launch_bounds__(256) void scan_part_kern(const int* __restrict__ deg,
                                                      int* __restrict__ bsum, int N) {
    __shared__ int sdata[256];
    int t = threadIdx.x;
    int base = blockIdx.x * SCAN_CHUNK + t * 4;
    int4 v;
    int sum = load4_sum(deg, base, N, &v);
    sdata[t] = sum;
    __syncthreads();
#pragma unroll
    for (int off = 128; off > 0; off >>= 1) {
        if (t < off) sdata[t] += sdata[t + off];
        __syncthreads();
    }
    if (t == 0) bsum[blockIdx.x] = sdata[0];
}

// Single small block: exclusive scan of nb (<=128) block sums; row_off[N]=total.
__global__ __launch_bounds__(128) void scan_top_kern(int* __restrict__ bsum,
                                                     int* __restrict__ row_off,
                                                     int nb, int N) {
    __shared__ int sdata[128];
    int t = threadIdx.x;
    int own = (t < nb) ? bsum[t] : 0;
    sdata[t] = own;
    __syncthreads();
#pragma unroll
    for (int off = 1; off < 128; off <<= 1) {
        int v = sdata[t];
        int add = (t >= off) ? sdata[t - off] : 0;
        __syncthreads();
        sdata[t] = v + add;
        __syncthreads();
    }
    if (t < nb) bsum[t] = sdata[t] - own;   // exclusive
    if (t == 127) row_off[N] = sdata[127];  // total == E
}

// Re-scan locally, add block offset; write row_off + ABSOLUTE cursor + dinv.
__global__ __launch_bounds__(256) void scan_apply_kern(const int* __restrict__ deg,
                                                       const int* __restrict__ bsum,
                                                       int* __restrict__ row_off,
                                                       int* __restrict__ cursor,
                                                       float* __restrict__ dinv, int N) {
    __shared__ int sdata[256];
    int t = threadIdx.x;
    int base = blockIdx.x * SCAN_CHUNK + t * 4;
    int4 v;
    int sum = load4_sum(deg, base, N, &v);
    sdata[t] = sum;
    __syncthreads();
#pragma unroll
    for (int off = 1; off < 256; off <<= 1) {
        int x = sdata[t];
        int add = (t >= off) ? sdata[t - off] : 0;
        __syncthreads();
        sdata[t] = x + add;
        __syncthreads();
    }
    int run = bsum[blockIdx.x] + sdata[t] - sum;  // global exclusive prefix
    if (base + 0 < N) { row_off[base + 0] = run; cursor[base + 0] = run; dinv[base + 0] = rsqrtf((float)(v.x + 1)); run += v.x; }
    if (base + 1 < N) { row_off[base + 1] = run; cursor[base + 1] = run; dinv[base + 1] = rsqrtf((float)(v.y + 1)); run += v.y; }
    if (base + 2 < N) { row_off[base + 2] = run; cursor[base + 2] = run; dinv[base + 2] = rsqrtf((float)(v.z + 1)); run += v.z; }
    if (base + 3 < N) { row_off[base + 3] = run; cursor[base + 3] = run; dinv[base + 3] = rsqrtf((float)(v.w + 1)); }
}

// Range-filtered CSR fill: block b -> dst range b%NRANGE, edge slice b/NRANGE.
// cursor holds absolute csr offsets. Writes land in the range's ~E/8 window.
__global__ __launch_bounds__(FT4) void fill4_kern(const int* __restrict__ src,
                                                  const int* __restrict__ dst,
                                                  int* __restrict__ cursor,
                                                  int* __restrict__ csr, int N, int E) {
    int b = blockIdx.x;
    int r = b & (NRANGE - 1);
    int s = b >> 3;                       // slice 0..NSLICE-1
    int lo = (int)(((long long)N * r) / NRANGE);
    int hi = (int)(((long long)N * (r + 1)) / NRANGE);
    unsigned len = (unsigned)(hi - lo);

    int E4 = E >> 2;
    int per = (E4 + NSLICE - 1) / NSLICE;
    int i0 = s * per;
    int i1 = i0 + per; if (i1 > E4) i1 = E4;
    const int4* d4 = (const int4*)dst;
    const int4* s4 = (const int4*)src;
    for (int i = i0 + threadIdx.x; i < i1; i += FT4) {
        int4 dv = d4[i];
        int4 sv = s4[i];
        if ((unsigned)(dv.x - lo) < len) { int p = atomicAdd(&cursor[dv.x], 1); csr[p] = sv.x; }
        if ((unsigned)(dv.y - lo) < len) { int p = atomicAdd(&cursor[dv.y], 1); csr[p] = sv.y; }
        if ((unsigned)(dv.z - lo) < len) { int p = atomicAdd(&cursor[dv.z], 1); csr[p] = sv.z; }
        if ((unsigned)(dv.w - lo) < len) { int p = atomicAdd(&cursor[dv.w], 1); csr[p] = sv.w; }
    }
    if (s == 0) {  // scalar tail (E not multiple of 4): one block per range
        for (int i = (E4 << 2) + threadIdx.x; i < E; i += FT4) {
            int d = dst[i];
            if ((unsigned)(d - lo) < len) { int p = atomicAdd(&cursor[d], 1); csr[p] = src[i]; }
        }
    }
}

// H[M,128](bf16) = X[M,128](fp32) @ W[128,128](fp32). 64 rows x 128 cols/block.
// K chunked by GK=32: LDS = 24 KB -> 6 blocks/CU.
__global__ __launch_bounds__(256) void gemm128_kern(const float* __restrict__ X,
                                                    const float* __restrict__ W,
                                                    uint2* __restrict__ H16, int M) {
    __shared__ float xs[64][GK];      // 8 KB
    __shared__ float wsm[GK][128];    // 16 KB
    int tid = threadIdx.x;
    int block_row = blockIdx.x * 64;
    int tx = tid & 31;
    int ty = tid >> 5;

    float4 acc[8];
#pragma unroll
    for (int i = 0; i < 8; ++i) acc[i] = make_float4(0.f, 0.f, 0.f, 0.f);

    for (int k0 = 0; k0 < 128; k0 += GK) {
        __syncthreads();  // protect previous chunk's LDS reads
        {
            const float4* W4 = (const float4*)(W + (size_t)k0 * 128);
            float4* w4 = (float4*)wsm;
#pragma unroll
            for (int i = 0; i < 4; ++i) w4[tid + 256 * i] = W4[tid + 256 * i];
        }
        {
#pragma unroll
            for (int i = 0; i < 2; ++i) {
                int idx = tid + 256 * i;   // 0..511
                int r = idx >> 3;          // 0..63
                int c = idx & 7;           // float4 within chunk
                int grow = block_row + r;
                float4 v = make_float4(0.f, 0.f, 0.f, 0.f);
                if (grow < M) v = ((const float4*)X)[(size_t)grow * 32 + (k0 >> 2) + c];
                ((float4*)xs)[idx] = v;
            }
        }
        __syncthreads();

#pragma unroll 4
        for (int kk = 0; kk < GK; ++kk) {
            float4 wv = ((float4*)&wsm[kk][0])[tx];
            float xr[8];
#pragma unroll
            for (int i = 0; i < 8; ++i) xr[i] = xs[ty * 8 + i][kk];
#pragma unroll
            for (int i = 0; i < 8; ++i) {
                acc[i].x = fmaf(xr[i], wv.x, acc[i].x);
                acc[i].y = fmaf(xr[i], wv.y, acc[i].y);
                acc[i].z = fmaf(xr[i], wv.z, acc[i].z);
                acc[i].w = fmaf(xr[i], wv.w, acc[i].w);
            }
        }
    }

#pragma unroll
    for (int i = 0; i < 8; ++i) {
        int grow = block_row + ty * 8 + i;
        if (grow < M) H16[(size_t)grow * 32 + tx] = pack4_bf16(acc[i]);
    }
}

// One wave per node, h in bf16 (256 B rows). 16-edge chunks: per-lane load
// src + dinv[src], shfl {src, norm}, 8 independent half-split uint2 gathers.
__global__ __launch_bounds__(256) void agg_kern(const int* __restrict__ row_off,
                                                const int* __restrict__ csr,
                                                const float* __restrict__ dinv,
                                                const uint2* __restrict__ h16,
                                                const float* __restrict__ bias,
                                                void* __restrict__ z,
                                                int N, int do_relu, int out_bf16) {
    int wave = (blockIdx.x * blockDim.x + threadIdx.x) >> 6;
    int lane = threadIdx.x & (WAVE - 1);
    if (wave >= N) return;
    int v = wave;
    int half = lane >> 5;    // lanes 0-31: even edge slots, 32-63: odd slots
    int l32 = lane & 31;
    int beg = row_off[v];
    int degv = row_off[v + 1] - beg;
    float dv = dinv[v];

    float4 acc = make_float4(0.f, 0.f, 0.f, 0.f);

    for (int base = 0; base < degv; base += WAVE) {
        int cnt = degv - base; if (cnt > WAVE) cnt = WAVE;
        int s_lane = 0;
        float n_lane = 0.f;
        if (lane < cnt) {
            s_lane = csr[beg + base + lane];       // coalesced
            n_lane = dinv[s_lane] * dv;            // dinv: 400 KB, L2-resident
        }
        for (int j = 0; j < cnt; j += 16) {
            int   sidx[8];
            float nn[8];
#pragma unroll
            for (int u = 0; u < 8; ++u) {
                int sl = j + 2 * u + half;          // slot in [j, j+16)
                sidx[u] = __shfl(s_lane, sl);
                nn[u]   = __shfl(n_lane, sl);
            }
            uint2 hv[8];
#pragma unroll
            for (int u = 0; u < 8; ++u)             // 8 independent 512 B gathers
                hv[u] = h16[(size_t)sidx[u] * 32 + l32];
#pragma unroll
            for (int u = 0; u < 8; ++u) {
                float4 f = unpack4_bf16(hv[u]);
                acc.x = fmaf(f.x, nn[u], acc.x);
                acc.y = fmaf(f.y, nn[u], acc.y);
                acc.z = fmaf(f.z, nn[u], acc.z);
                acc.w = fmaf(f.w, nn[u], acc.w);
            }
        }
    }

    // combine the two halves (lane^32)
    acc.x += __shfl_xor(acc.x, 32, 64);
    acc.y += __shfl_xor(acc.y, 32, 64);
    acc.z += __shfl_xor(acc.z, 32, 64);
    acc.w += __shfl_xor(acc.w, 32, 64);

    float ss = dv * dv;
    float4 hv = unpack4_bf16(h16[(size_t)v * 32 + l32]);
    float4 bv = ((const float4*)bias)[l32];
    acc.x = fmaf(hv.x, ss, acc.x) + bv.x;
    acc.y = fmaf(hv.y, ss, acc.y) + bv.y;
    acc.z = fmaf(hv.z, ss, acc.z) + bv.z;
    acc.w = fmaf(hv.w, ss, acc.w) + bv.w;
    if (do_relu) {
        acc.x = fmaxf(acc.x, 0.f); acc.y = fmaxf(acc.y, 0.f);
        acc.z = fmaxf(acc.z, 0.f); acc.w = fmaxf(acc.w, 0.f);
    }
    if (half == 0) {
        if (out_bf16) ((uint2*)z)[(size_t)v * 32 + l32] = pack4_bf16(acc);
        else          ((float4*)z)[(size_t)v * 32 + l32] = acc;
    }
}

// Four label edges per wave (2 per half-wave), z2 in bf16 (256 B rows).
__global__ __launch_bounds__(256) void decode_kern(const int* __restrict__ s_idx,
                                                   const int* __restrict__ d_idx,
                                                   const uint2* __restrict__ z16,
                                                   float* __restrict__ out, int EL) {
    int lane = threadIdx.x & (WAVE - 1);
    int wave = (blockIdx.x * blockDim.x + threadIdx.x) >> 6;
    int half = lane >> 5;
    int l32 = lane & 31;
    int e0 = wave * 4 + half;      // this half-wave handles e0 and e0+2
    int e1 = e0 + 2;

    int s0 = 0, d0 = 0, s1 = 0, d1 = 0;
    if (e0 < EL) { s0 = s_idx[e0]; d0 = d_idx[e0]; }
    if (e1 < EL) { s1 = s_idx[e1]; d1 = d_idx[e1]; }
    uint2 pa0 = z16[(size_t)s0 * 32 + l32];
    uint2 pb0 = z16[(size_t)d0 * 32 + l32];
    uint2 pa1 = z16[(size_t)s1 * 32 + l32];
    uint2 pb1 = z16[(size_t)d1 * 32 + l32];
    float4 a0 = unpack4_bf16(pa0), b0 = unpack4_bf16(pb0);
    float4 a1 = unpack4_bf16(pa1), b1 = unpack4_bf16(pb1);
    float p0 = a0.x * b0.x + a0.y * b0.y + a0.z * b0.z + a0.w * b0.w;
    float p1 = a1.x * b1.x + a1.y * b1.y + a1.z * b1.z + a1.w * b1.w;
#pragma unroll
    for (int off = 16; off > 0; off >>= 1) {
        p0 += __shfl_xor(p0, off, 64);   // stays within the 32-lane half
        p1 += __shfl_xor(p1, off, 64);
    }
    if (l32 == 0) {
        if (e0 < EL) out[e0] = p0;
        if (e1 < EL) out[e1] = p1;
    }
}

extern "C" void kernel_launch(void* const* d_in, const int* in_sizes, int n_in,
                              void* d_out, int out_size, void* d_ws, size_t ws_size,
                              hipStream_t stream) {
    const float* x   = (const float*)d_in[0];
    const int*   ei  = (const int*)d_in[1];
    const int*   eli = (const int*)d_in[2];
    const float* W1  = (const float*)d_in[3];
    const float* b1  = (const float*)d_in[4];
    const float* W2  = (const float*)d_in[5];
    const float* b2  = (const float*)d_in[6];
    float* out = (float*)d_out;

    int N  = in_sizes[0] / 128;
    int E  = in_sizes[1] / 2;
    int EL = in_sizes[2] / 2;
    const int* src = ei;
    const int* dst = ei + E;
    const int* ls  = eli;
    const int* ld  = eli + EL;

    char* ws = (char*)d_ws;
    float* dinv    = (float*)(ws);
    int*   deg     = (int*)(ws + (512 << 10));
    int*   row_off = (int*)(ws + (1024 << 10));
    int*   cursor  = (int*)(ws + (1536 << 10));
    int*   csr     = (int*)(ws + (2048 << 10));   // ends ~8.5 MB
    int*   bsum    = (int*)(ws + (8704 << 10));
    uint2* hbuf    = (uint2*)(ws + (24u << 20));  // bf16 h (25.6 MB)
    char*  zraw    = ws + (56u << 20);            // z1 fp32 / z2 bf16 (51.2 MB)
    float* z1      = (float*)zraw;
    uint2* z2      = (uint2*)zraw;

    int nodeGrid = (N + 255) / 256;
    int edgeGrid = (E + 255) / 256;
    int gemmGrid = (N + 63) / 64;
    int aggGrid  = (N + 3) / 4;   // 4 waves/block, 1 wave/node
    int nbScan   = (N + SCAN_CHUNK - 1) / SCAN_CHUNK;  // 98 for N=100K (<=128)

    // CSR build (shared by both layers)
    zero1_kern<<<nodeGrid, 256, 0, stream>>>(deg, N);
    deg_count_kern<<<edgeGrid, 256, 0, stream>>>(dst, deg, E);
    scan_part_kern<<<nbScan, 256, 0, stream>>>(deg, bsum, N);
    scan_top_kern<<<1, 128, 0, stream>>>(bsum, row_off, nbScan, N);
    scan_apply_kern<<<nbScan, 256, 0, stream>>>(deg, bsum, row_off, cursor, dinv, N);
    fill4_kern<<<NRANGE * NSLICE, FT4, 0, stream>>>(src, dst, cursor, csr, N, E);

    // layer 1: h1(bf16) = x @ W1 ; z1(fp32) = relu(agg(h1) + b1)
    gemm128_kern<<<gemmGrid, 256, 0, stream>>>(x, W1, hbuf, N);
    agg_kern<<<aggGrid, 256, 0, stream>>>(row_off, csr, dinv, hbuf, b1, (void*)z1, N, 1, 0);

    // layer 2: h2(bf16) = z1 @ W2 ; z2(bf16) = agg(h2) + b2
    gemm128_kern<<<gemmGrid, 256, 0, stream>>>(z1, W2, hbuf, N);
    agg_kern<<<aggGrid, 256, 0, stream>>>(row_off, csr, dinv, hbuf, b2, (void*)z2, N, 0, 1);

    // decode: 4 edges per wave, bf16 gathers
    decode_kern<<<(EL + 15) / 16, 256, 0, stream>>>(ls, ld, z2, out, EL);
}